// Round 9
// baseline (472.023 us; speedup 1.0000x reference)
//
#include <hip/hip_runtime.h>
#include <math.h>

#define NHEAD 12
#define DH 64
#define S_LEN 4096
#define B_SZ 2
#define D_MODEL 768
#define FF_DIM 3072
#define WINSZ 128
#define NGLB 32
#define NEGV -1e9f
#define NQC 6291456L

typedef __attribute__((ext_vector_type(8))) short bf16x8;
typedef __attribute__((ext_vector_type(4))) float floatx4;

__device__ __forceinline__ unsigned short f2bf(float x) {
    union { float f; unsigned u; } v; v.f = x;
    unsigned r = v.u + 0x7fffu + ((v.u >> 16) & 1u);
    return (unsigned short)(r >> 16);
}
__device__ __forceinline__ float bf2f(unsigned short x) {
    union { unsigned u; float f; } v; v.u = ((unsigned)x) << 16;
    return v.f;
}

// fast GELU (tanh approx, |err| vs exact-erf gelu < ~3e-3)
__device__ __forceinline__ float gelu_f(float x) {
    const float y = 1.5957691216f * (x + 0.044715f * x * x * x);  // 2*0.79788456*(...)
    const float t = __expf(y);
    return x * t / (t + 1.f) /* = 0.5x(1+tanh(y/2)) */;
}

__device__ __forceinline__ void async_copy16(const unsigned short* g, unsigned short* l) {
    __builtin_amdgcn_global_load_lds(
        (const __attribute__((address_space(1))) void*)g,
        (__attribute__((address_space(3))) void*)l, 16, 0, 0);
}

// ---------------------------------------------------------------------------
// fp32 -> bf16 elementwise
// ---------------------------------------------------------------------------
__global__ __launch_bounds__(256) void conv_k(
    const float* __restrict__ x, unsigned short* __restrict__ y, long n)
{
    long i = ((long)blockIdx.x * 256 + threadIdx.x) * 4;
    if (i >= n) return;
    float4 v = *(const float4*)(x + i);
    ushort4 o;
    o.x = f2bf(v.x); o.y = f2bf(v.y); o.z = f2bf(v.z); o.w = f2bf(v.w);
    *(ushort4*)(y + i) = o;
}

// ---------------------------------------------------------------------------
// concat 3 x 768 biases -> 2304
// ---------------------------------------------------------------------------
__global__ __launch_bounds__(256) void bcat_k(
    const float* __restrict__ a, const float* __restrict__ b,
    const float* __restrict__ c, float* __restrict__ o)
{
    int i = blockIdx.x * 256 + threadIdx.x;
    if (i < 768) o[i] = a[i];
    else if (i < 1536) o[i] = b[i - 768];
    else if (i < 2304) o[i] = c[i - 1536];
}

// ---------------------------------------------------------------------------
// W (KxN fp32) -> WT (NxK bf16)
// ---------------------------------------------------------------------------
__global__ __launch_bounds__(256) void transpose_k(
    const float* __restrict__ W, unsigned short* __restrict__ WT, int K, int N)
{
    __shared__ float tile[32][33];
    const int tx = threadIdx.x, ty = threadIdx.y;
    const int n0 = blockIdx.x * 32, k0 = blockIdx.y * 32;
#pragma unroll
    for (int i = 0; i < 4; ++i)
        tile[ty + 8 * i][tx] = W[(long)(k0 + ty + 8 * i) * N + n0 + tx];
    __syncthreads();
#pragma unroll
    for (int i = 0; i < 4; ++i)
        WT[(long)(n0 + ty + 8 * i) * K + k0 + tx] = f2bf(tile[tx][ty + 8 * i]);
}

// ---------------------------------------------------------------------------
// V (B,NH,S,DH) bf16 -> Vt (B,NH,DH,S) bf16
// ---------------------------------------------------------------------------
__global__ __launch_bounds__(256) void vt_k(
    const unsigned short* __restrict__ v, unsigned short* __restrict__ vt)
{
    const int bh = blockIdx.y;
    const int s0 = blockIdx.x * 32;
    const int w = threadIdx.x >> 6, lane = threadIdx.x & 63;
    const unsigned short* src = v + ((long)bh * S_LEN + s0 + w * 8) * DH + lane;
    unsigned short r[8];
#pragma unroll
    for (int j = 0; j < 8; ++j) r[j] = src[j * DH];
    unsigned short* dst = vt + ((long)bh * DH + lane) * S_LEN + s0 + w * 8;
    ushort4 lo, hi;
    lo.x = r[0]; lo.y = r[1]; lo.z = r[2]; lo.w = r[3];
    hi.x = r[4]; hi.y = r[5]; hi.z = r[6]; hi.w = r[7];
    *(ushort4*)dst = lo;
    *(ushort4*)(dst + 4) = hi;
}

// ---------------------------------------------------------------------------
// bf16 MFMA GEMM: C = epi(A @ BT^T + bias). XCD-clustered 1D swizzle.
// EPI 1: fast gelu -> bf16
// EPI 2: fused QKV scatter (part/scale/base hoisted; block never straddles
//        a 768 boundary since 768 = 6*128) -> bf16
// ---------------------------------------------------------------------------
template <int EPI>
__global__ __launch_bounds__(256) void gemm_bf(
    const unsigned short* __restrict__ A, const unsigned short* __restrict__ BT,
    const float* __restrict__ bias, void* __restrict__ out,
    int M, int N, int K, int nx)
{
    __shared__ unsigned short As[128 * 32];
    __shared__ unsigned short Bs[128 * 32];
    const int tid = threadIdx.x;
    const int wave = tid >> 6, lane = tid & 63;
    const int t8 = (blockIdx.x & 7) * (gridDim.x >> 3) + (blockIdx.x >> 3);
    const int m0 = (t8 / nx) * 128, n0 = (t8 % nx) * 128;
    const int wr = (wave >> 1) * 64, wc = (wave & 1) * 64;

    floatx4 acc[4][4];
#pragma unroll
    for (int i = 0; i < 4; ++i)
#pragma unroll
        for (int j = 0; j < 4; ++j) acc[i][j] = (floatx4){0.f, 0.f, 0.f, 0.f};

    const int srow = lane >> 2;
    const int schk = (((lane & 3) ^ (srow & 3))) * 8;
    const int r = lane & 15;
    const int q8 = ((lane >> 4) ^ (lane & 3)) * 8;

    for (int k0 = 0; k0 < K; k0 += 32) {
#pragma unroll
        for (int gi = 0; gi < 2; ++gi) {
            const int g = wave * 2 + gi;
            async_copy16(A + (long)(m0 + g * 16 + srow) * K + k0 + schk, &As[g * 512]);
            async_copy16(BT + (long)(n0 + g * 16 + srow) * K + k0 + schk, &Bs[g * 512]);
        }
        __syncthreads();

        bf16x8 af[4], bfr[4];
#pragma unroll
        for (int i = 0; i < 4; ++i) {
            af[i]  = *(const bf16x8*)&As[(wr + i * 16 + r) * 32 + q8];
            bfr[i] = *(const bf16x8*)&Bs[(wc + i * 16 + r) * 32 + q8];
        }
#pragma unroll
        for (int i = 0; i < 4; ++i)
#pragma unroll
            for (int j = 0; j < 4; ++j)
                acc[i][j] = __builtin_amdgcn_mfma_f32_16x16x32_bf16(
                    af[i], bfr[j], acc[i][j], 0, 0, 0);
        __syncthreads();
    }

    const int col_l = lane & 15, row_l = (lane >> 4) * 4;

    if (EPI == 1) {
#pragma unroll
        for (int i = 0; i < 4; ++i) {
            const int mb = m0 + wr + i * 16 + row_l;
#pragma unroll
            for (int rg = 0; rg < 4; ++rg) {
                unsigned short* orow = (unsigned short*)out + (long)(mb + rg) * N;
#pragma unroll
                for (int j = 0; j < 4; ++j) {
                    const int n = n0 + wc + j * 16 + col_l;
                    orow[n] = f2bf(gelu_f(acc[i][j][rg] + bias[n]));
                }
            }
        }
    } else {
        // QKV scatter: part uniform per block
        const int part = (n0 >= 1536) ? 2 : (n0 >= 768 ? 1 : 0);
        const float sc = (part == 0) ? 0.125f : 1.f;
        unsigned short* qkv = (unsigned short*)out + (long)part * NQC;
        long coloff[4];
        float bv[4];
#pragma unroll
        for (int j = 0; j < 4; ++j) {
            const int n = n0 + wc + j * 16 + col_l;
            const int nn = n - part * 768;
            coloff[j] = (long)(nn >> 6) * (S_LEN * DH) + (nn & 63);
            bv[j] = bias[n];
        }
#pragma unroll
        for (int i = 0; i < 4; ++i) {
            const int mb = m0 + wr + i * 16 + row_l;
#pragma unroll
            for (int rg = 0; rg < 4; ++rg) {
                const int m = mb + rg;
                const long rowoff = (long)(m >> 12) * (NHEAD * S_LEN * DH)
                                  + (long)(m & 4095) * DH;
#pragma unroll
                for (int j = 0; j < 4; ++j)
                    qkv[rowoff + coloff[j]] = f2bf((acc[i][j][rg] + bv[j]) * sc);
            }
        }
    }
}

// ---------------------------------------------------------------------------
// Split-K (x2) bf16 MFMA GEMM: raw fp32 partials, no epilogue.
// ---------------------------------------------------------------------------
__global__ __launch_bounds__(256) void gemm_sp(
    const unsigned short* __restrict__ A, const unsigned short* __restrict__ BT,
    float* __restrict__ p0, float* __restrict__ p1,
    int M, int N, int K2, int nx, int ntile)
{
    __shared__ unsigned short As[128 * 32];
    __shared__ unsigned short Bs[128 * 32];
    const int tid = threadIdx.x;
    const int wave = tid >> 6, lane = tid & 63;
    const int t8 = (blockIdx.x & 7) * (gridDim.x >> 3) + (blockIdx.x >> 3);
    const int slice = t8 >= ntile;
    const int tile = t8 - slice * ntile;
    const int m0 = (tile / nx) * 128, n0 = (tile % nx) * 128;
    const int kbeg = slice * K2, kend = kbeg + K2;
    float* P = slice ? p1 : p0;
    const int wr = (wave >> 1) * 64, wc = (wave & 1) * 64;

    floatx4 acc[4][4];
#pragma unroll
    for (int i = 0; i < 4; ++i)
#pragma unroll
        for (int j = 0; j < 4; ++j) acc[i][j] = (floatx4){0.f, 0.f, 0.f, 0.f};

    const int srow = lane >> 2;
    const int schk = (((lane & 3) ^ (srow & 3))) * 8;
    const int r = lane & 15;
    const int q8 = ((lane >> 4) ^ (lane & 3)) * 8;
    const long Kl = (long)K2 * 2;

    for (int k0 = kbeg; k0 < kend; k0 += 32) {
#pragma unroll
        for (int gi = 0; gi < 2; ++gi) {
            const int g = wave * 2 + gi;
            async_copy16(A + (long)(m0 + g * 16 + srow) * Kl + k0 + schk, &As[g * 512]);
            async_copy16(BT + (long)(n0 + g * 16 + srow) * Kl + k0 + schk, &Bs[g * 512]);
        }
        __syncthreads();

        bf16x8 af[4], bfr[4];
#pragma unroll
        for (int i = 0; i < 4; ++i) {
            af[i]  = *(const bf16x8*)&As[(wr + i * 16 + r) * 32 + q8];
            bfr[i] = *(const bf16x8*)&Bs[(wc + i * 16 + r) * 32 + q8];
        }
#pragma unroll
        for (int i = 0; i < 4; ++i)
#pragma unroll
            for (int j = 0; j < 4; ++j)
                acc[i][j] = __builtin_amdgcn_mfma_f32_16x16x32_bf16(
                    af[i], bfr[j], acc[i][j], 0, 0, 0);
        __syncthreads();
    }

    const int col_l = lane & 15, row_l = (lane >> 4) * 4;
#pragma unroll
    for (int i = 0; i < 4; ++i)
#pragma unroll
        for (int j = 0; j < 4; ++j) {
            const int n = n0 + wc + j * 16 + col_l;
#pragma unroll
            for (int rg = 0; rg < 4; ++rg) {
                const int m = m0 + wr + i * 16 + row_l + rg;
                P[(long)m * N + n] = acc[i][j][rg];
            }
        }
}

// ---------------------------------------------------------------------------
// MFMA band attention. One block per (b,h,chunk); 4 waves x 32 queries.
// ---------------------------------------------------------------------------
__global__ __launch_bounds__(256) void band_mfma_k(
    const unsigned short* __restrict__ q, const unsigned short* __restrict__ k,
    const unsigned short* __restrict__ vt, const float* __restrict__ am,
    unsigned short* __restrict__ ctx)
{
    __shared__ unsigned short Ks[32 * 72];
    __shared__ unsigned short Vs[64 * 40];
    __shared__ unsigned short Ps[4][32 * 40];

    const int blk = blockIdx.x;
    const int c = blk & 31;
    const int h = (blk >> 5) % NHEAD;
    const int b = blk / (32 * NHEAD);
    const int tid = threadIdx.x;
    const int wave = tid >> 6, lane = tid & 63;
    const long bh = (long)b * NHEAD + h;

    const unsigned short* kh  = k + bh * S_LEN * DH;
    const unsigned short* vth = vt + bh * (long)DH * S_LEN;
    const float* amb = am + (long)b * S_LEN;

    const int q0 = c * WINSZ + wave * 32;
    const int ln15 = lane & 15, ln4 = lane >> 4;

    bf16x8 qf[2][2];
#pragma unroll
    for (int nt = 0; nt < 2; ++nt)
#pragma unroll
        for (int ks = 0; ks < 2; ++ks)
            qf[nt][ks] = *(const bf16x8*)(q + (bh * S_LEN + q0 + nt * 16 + ln15) * DH
                                          + ks * 32 + ln4 * 8);

    floatx4 o[4][2];
#pragma unroll
    for (int mt = 0; mt < 4; ++mt)
#pragma unroll
        for (int nt = 0; nt < 2; ++nt) o[mt][nt] = (floatx4){0.f, 0.f, 0.f, 0.f};
    float m_r[2] = {-1e30f, -1e30f}, l_r[2] = {0.f, 0.f};

    const int sk_key = tid >> 3, sk_ch = tid & 7;
    const int sv_dim = tid & 63, sv_ch = tid >> 6;
    const bf16x8 zero8 = {0, 0, 0, 0, 0, 0, 0, 0};

    for (int tile = 0; tile < 13; ++tile) {
        const bool glob = (tile == 12);
        const int kbase = glob ? 0 : (c * WINSZ - WINSZ + tile * 32);

        __syncthreads();
        {
            int kpos = kbase + sk_key;
            bf16x8 val = zero8;
            if ((unsigned)kpos < (unsigned)S_LEN)
                val = *(const bf16x8*)(kh + (long)kpos * DH + sk_ch * 8);
            *(bf16x8*)(&Ks[sk_key * 72 + sk_ch * 8]) = val;
        }
        {
            int kc = kbase + sv_ch * 8;
            bf16x8 val = zero8;
            if (kc >= 0 && kc + 8 <= S_LEN)
                val = *(const bf16x8*)(vth + (long)sv_dim * S_LEN + kc);
            *(bf16x8*)(&Vs[sv_dim * 40 + sv_ch * 8]) = val;
        }
        __syncthreads();

        bf16x8 ak[2][2];
#pragma unroll
        for (int mt = 0; mt < 2; ++mt)
#pragma unroll
            for (int ks = 0; ks < 2; ++ks)
                ak[mt][ks] = *(const bf16x8*)(&Ks[(mt * 16 + ln15) * 72 + ks * 32 + ln4 * 8]);

        floatx4 s[2][2];
#pragma unroll
        for (int mt = 0; mt < 2; ++mt)
#pragma unroll
            for (int nt = 0; nt < 2; ++nt) {
                floatx4 acc = (floatx4){0.f, 0.f, 0.f, 0.f};
                acc = __builtin_amdgcn_mfma_f32_16x16x32_bf16(ak[mt][0], qf[nt][0], acc, 0, 0, 0);
                acc = __builtin_amdgcn_mfma_f32_16x16x32_bf16(ak[mt][1], qf[nt][1], acc, 0, 0, 0);
                s[mt][nt] = acc;
            }

#pragma unroll
        for (int mt = 0; mt < 2; ++mt) {
            const int kp0 = kbase + mt * 16 + ln4 * 4;
#pragma unroll
            for (int rg = 0; rg < 4; ++rg) {
                const int kpos = kp0 + rg;
                const bool kin = (unsigned)kpos < (unsigned)S_LEN;
                const float amv = kin ? amb[kpos] : 0.f;
#pragma unroll
                for (int nt = 0; nt < 2; ++nt) {
                    const int qpos = q0 + nt * 16 + ln15;
                    const int dlt = kpos > qpos ? kpos - qpos : qpos - kpos;
                    const bool valid = glob || (kpos >= NGLB && kin && dlt <= WINSZ);
                    s[mt][nt][rg] = valid ? s[mt][nt][rg] + amv : NEGV;
                }
            }
        }

        float alpha[2];
#pragma unroll
        for (int nt = 0; nt < 2; ++nt) {
            float mx = s[0][nt][0];
#pragma unroll
            for (int rg = 1; rg < 4; ++rg) mx = fmaxf(mx, s[0][nt][rg]);
#pragma unroll
            for (int rg = 0; rg < 4; ++rg) mx = fmaxf(mx, s[1][nt][rg]);
            mx = fmaxf(mx, __shfl_xor(mx, 16));
            mx = fmaxf(mx, __shfl_xor(mx, 32));
            const float mn = fmaxf(m_r[nt], mx);
            alpha[nt] = __expf(m_r[nt] - mn);
            m_r[nt] = mn;
        }

#pragma unroll
        for (int nt = 0; nt < 2; ++nt) {
            float sum = 0.f;
#pragma unroll
            for (int mt = 0; mt < 2; ++mt) {
                ushort4 pk;
#pragma unroll
                for (int rg = 0; rg < 4; ++rg) {
                    const float p = __expf(s[mt][nt][rg] - m_r[nt]);
                    sum += p;
                    ((unsigned short*)&pk)[rg] = f2bf(p);
                }
                *(ushort4*)(&Ps[wave][(nt * 16 + ln15) * 40 + mt * 16 + ln4 * 4]) = pk;
            }
            sum += __shfl_xor(sum, 16);
            sum += __shfl_xor(sum, 32);
            l_r[nt] = l_r[nt] * alpha[nt] + sum;
        }

#pragma unroll
        for (int mt = 0; mt < 4; ++mt)
#pragma unroll
            for (int nt = 0; nt < 2; ++nt)
#pragma unroll
                for (int rg = 0; rg < 4; ++rg) o[mt][nt][rg] *= alpha[nt];

        bf16x8 av[4], bp[2];
#pragma unroll
        for (int mt = 0; mt < 4; ++mt)
            av[mt] = *(const bf16x8*)(&Vs[(mt * 16 + ln15) * 40 + ln4 * 8]);
#pragma unroll
        for (int nt = 0; nt < 2; ++nt)
            bp[nt] = *(const bf16x8*)(&Ps[wave][(nt * 16 + ln15) * 40 + ln4 * 8]);
#pragma unroll
        for (int mt = 0; mt < 4; ++mt)
#pragma unroll
            for (int nt = 0; nt < 2; ++nt)
                o[mt][nt] = __builtin_amdgcn_mfma_f32_16x16x32_bf16(
                    av[mt], bp[nt], o[mt][nt], 0, 0, 0);
    }

    const float inv0 = 1.f / l_r[0], inv1 = 1.f / l_r[1];
#pragma unroll
    for (int nt = 0; nt < 2; ++nt) {
        const float inv = nt ? inv1 : inv0;
        const long row = (long)b * S_LEN + q0 + nt * 16 + ln15;
#pragma unroll
        for (int mt = 0; mt < 4; ++mt) {
            ushort4 ov;
#pragma unroll
            for (int rg = 0; rg < 4; ++rg)
                ((unsigned short*)&ov)[rg] = f2bf(o[mt][nt][rg] * inv);
            *(ushort4*)(ctx + row * D_MODEL + h * DH + mt * 16 + ln4 * 4) = ov;
        }
    }
}

// ---------------------------------------------------------------------------
// MFMA global-query attention. One block per (b,h); 8 waves x 512 keys/iter.
// ---------------------------------------------------------------------------
__global__ __launch_bounds__(512) void glob_mfma_k(
    const unsigned short* __restrict__ q, const unsigned short* __restrict__ k,
    const unsigned short* __restrict__ vt, const float* __restrict__ am,
    unsigned short* __restrict__ ctx)
{
    __shared__ unsigned short Ps[8][32 * 72];
    __shared__ float Om[64 * 36];
    __shared__ float mW[8][32], lW[8][32], lTot[32];

    const int bh = blockIdx.x;
    const int b = bh / NHEAD, h = bh % NHEAD;
    const int tid = threadIdx.x;
    const int wave = tid >> 6, lane = tid & 63;
    const int ln15 = lane & 15, ln4 = lane >> 4;

    const unsigned short* kh  = k + (long)bh * S_LEN * DH;
    const unsigned short* vth = vt + (long)bh * DH * S_LEN;
    const float* amb = am + (long)b * S_LEN;

    bf16x8 qf[2][2];
#pragma unroll
    for (int nt = 0; nt < 2; ++nt)
#pragma unroll
        for (int ks = 0; ks < 2; ++ks)
            qf[nt][ks] = *(const bf16x8*)(q + ((long)bh * S_LEN + nt * 16 + ln15) * DH
                                          + ks * 32 + ln4 * 8);

    floatx4 o[4][2];
#pragma unroll
    for (int mt = 0; mt < 4; ++mt)
#pragma unroll
        for (int nt = 0; nt < 2; ++nt) o[mt][nt] = (floatx4){0.f, 0.f, 0.f, 0.f};
    float m_r[2] = {-1e30f, -1e30f}, l_r[2] = {0.f, 0.f};

    for (int it = 0; it < 8; ++it) {
        const int kbase = it * 512 + wave * 64;

        bf16x8 ak[4][2];
#pragma unroll
        for (int mt = 0; mt < 4; ++mt)
#pragma unroll
            for (int ks = 0; ks < 2; ++ks)
                ak[mt][ks] = *(const bf16x8*)(kh + (long)(kbase + mt * 16 + ln15) * DH
                                              + ks * 32 + ln4 * 8);

        floatx4 s[4][2];
#pragma unroll
        for (int mt = 0; mt < 4; ++mt)
#pragma unroll
            for (int nt = 0; nt < 2; ++nt) {
                floatx4 acc = (floatx4){0.f, 0.f, 0.f, 0.f};
                acc = __builtin_amdgcn_mfma_f32_16x16x32_bf16(ak[mt][0], qf[nt][0], acc, 0, 0, 0);
                acc = __builtin_amdgcn_mfma_f32_16x16x32_bf16(ak[mt][1], qf[nt][1], acc, 0, 0, 0);
                s[mt][nt] = acc;
            }

#pragma unroll
        for (int mt = 0; mt < 4; ++mt) {
            const int kp0 = kbase + mt * 16 + ln4 * 4;
#pragma unroll
            for (int rg = 0; rg < 4; ++rg) {
                const float amv = amb[kp0 + rg];
#pragma unroll
                for (int nt = 0; nt < 2; ++nt) s[mt][nt][rg] += amv;
            }
        }

        float alpha[2];
#pragma unroll
        for (int nt = 0; nt < 2; ++nt) {
            float mx = s[0][nt][0];
#pragma unroll
            for (int mt = 0; mt < 4; ++mt)
#pragma unroll
                for (int rg = 0; rg < 4; ++rg) mx = fmaxf(mx, s[mt][nt][rg]);
            mx = fmaxf(mx, __shfl_xor(mx, 16));
            mx = fmaxf(mx, __shfl_xor(mx, 32));
            const float mn = fmaxf(m_r[nt], mx);
            alpha[nt] = __expf(m_r[nt] - mn);
            m_r[nt] = mn;
        }

#pragma unroll
        for (int nt = 0; nt < 2; ++nt) {
            float sum = 0.f;
#pragma unroll
            for (int mt = 0; mt < 4; ++mt) {
                ushort4 pk;
#pragma unroll
                for (int rg = 0; rg < 4; ++rg) {
                    const float p = __expf(s[mt][nt][rg] - m_r[nt]);
                    sum += p;
                    ((unsigned short*)&pk)[rg] = f2bf(p);
                }
                *(ushort4*)(&Ps[wave][(nt * 16 + ln15) * 72 + mt * 16 + ln4 * 4]) = pk;
            }
            sum += __shfl_xor(sum, 16);
            sum += __shfl_xor(sum, 32);
            l_r[nt] = l_r[nt] * alpha[nt] + sum;
        }

#pragma unroll
        for (int mt = 0; mt < 4; ++mt)
#pragma unroll
            for (int nt = 0; nt < 2; ++nt)
#pragma unroll
                for (int rg = 0; rg < 4; ++rg) o[mt][nt][rg] *= alpha[nt];

        bf16x8 av[4][2], bp[2][2];
#pragma unroll
        for (int mt = 0; mt < 4; ++mt)
#pragma unroll
            for (int ks = 0; ks < 2; ++ks)
                av[mt][ks] = *(const bf16x8*)(vth + (long)(mt * 16 + ln15) * S_LEN
                                              + kbase + ks * 32 + ln4 * 8);
#pragma unroll
        for (int nt = 0; nt < 2; ++nt)
#pragma unroll
            for (int ks = 0; ks < 2; ++ks)
                bp[nt][ks] = *(const bf16x8*)(&Ps[wave][(nt * 16 + ln15) * 72
                                              + ks * 32 + ln4 * 8]);
#pragma unroll
        for (int mt = 0; mt < 4; ++mt)
#pragma unroll
            for (int nt = 0; nt < 2; ++nt) {
                o[mt][nt] = __builtin_amdgcn_mfma_f32_16x16x32_bf16(
                    av[mt][0], bp[nt][0], o[mt][nt], 0, 0, 0);
                o[mt][nt] = __builtin_amdgcn_mfma_f32_16x16x32_bf16(
                    av[mt][1], bp[nt][1], o[mt][nt], 0, 0, 0);
            }
    }

    if (ln4 == 0) {
#pragma unroll
        for (int nt = 0; nt < 2; ++nt) {
            mW[wave][nt * 16 + ln15] = m_r[nt];
            lW[wave][nt * 16 + ln15] = l_r[nt];
        }
    }
    for (int i = tid; i < 64 * 36; i += 512) Om[i] = 0.f;
    __syncthreads();

    float f[2];
#pragma unroll
    for (int nt = 0; nt < 2; ++nt) {
        const int qq = nt * 16 + ln15;
        float mt_ = mW[0][qq];
#pragma unroll
        for (int w = 1; w < 8; ++w) mt_ = fmaxf(mt_, mW[w][qq]);
        float lt = 0.f;
#pragma unroll
        for (int w = 0; w < 8; ++w) lt += __expf(mW[w][qq] - mt_) * lW[w][qq];
        f[nt] = __expf(m_r[nt] - mt_);
        if (wave == 0 && ln4 == 0) lTot[qq] = lt;
    }
#pragma unroll
    for (int mt = 0; mt < 4; ++mt)
#pragma unroll
        for (int nt = 0; nt < 2; ++nt)
#pragma unroll
            for (int rg = 0; rg < 4; ++rg) o[mt][nt][rg] *= f[nt];

    for (int wv = 0; wv < 8; ++wv) {
        if (wave == wv) {
#pragma unroll
            for (int mt = 0; mt < 4; ++mt)
#pragma unroll
                for (int nt = 0; nt < 2; ++nt)
#pragma unroll
                    for (int rg = 0; rg < 4; ++rg)
                        Om[(mt * 16 + ln4 * 4 + rg) * 36 + nt * 16 + ln15] += o[mt][nt][rg];
        }
        __syncthreads();
    }

    const int qq = tid >> 4, d0 = (tid & 15) * 4;
    const float inv = 1.f / lTot[qq];
    ushort4 ov;
#pragma unroll
    for (int i = 0; i < 4; ++i)
        ((unsigned short*)&ov)[i] = f2bf(Om[(d0 + i) * 36 + qq] * inv);
    *(ushort4*)(ctx + ((long)b * S_LEN + qq) * D_MODEL + h * DH + d0) = ov;
}

// ---------------------------------------------------------------------------
// Fused split-K reduce + bias + residual + LayerNorm.
// ---------------------------------------------------------------------------
__global__ __launch_bounds__(256) void ln2p_k(
    const float* __restrict__ p0, const float* __restrict__ p1,
    const float* __restrict__ bias, const float* __restrict__ resid,
    float* __restrict__ out, unsigned short* __restrict__ out_bf,
    const float* __restrict__ gw, const float* __restrict__ bw)
{
    __shared__ float red[256];
    const long row = blockIdx.x;
    const long base = row * D_MODEL;
    const int t = threadIdx.x;
    float v0 = p0[base + t]       + p1[base + t]       + bias[t]       + resid[base + t];
    float v1 = p0[base + t + 256] + p1[base + t + 256] + bias[t + 256] + resid[base + t + 256];
    float v2 = p0[base + t + 512] + p1[base + t + 512] + bias[t + 512] + resid[base + t + 512];

    red[t] = v0 + v1 + v2;
    __syncthreads();
    for (int off = 128; off; off >>= 1) {
        if (t < off) red[t] += red[t + off];
        __syncthreads();
    }
    const float mu = red[0] * (1.f / 768.f);
    __syncthreads();

    float d0 = v0 - mu, d1 = v1 - mu, d2 = v2 - mu;
    red[t] = d0 * d0 + d1 * d1 + d2 * d2;
    __syncthreads();
    for (int off = 128; off; off >>= 1) {
        if (t < off) red[t] += red[t + off];
        __syncthreads();
    }
    const float var = red[0] * (1.f / 768.f);
    const float rs = rsqrtf(var + 1e-12f);

    const float y0 = d0 * rs * gw[t] + bw[t];
    const float y1 = d1 * rs * gw[t + 256] + bw[t + 256];
    const float y2 = d2 * rs * gw[t + 512] + bw[t + 512];
    if (out) {
        float* y = out + base;
        y[t] = y0; y[t + 256] = y1; y[t + 512] = y2;
    }
    if (out_bf) {
        unsigned short* yb = out_bf + base;
        yb[t] = f2bf(y0); yb[t + 256] = f2bf(y1); yb[t + 512] = f2bf(y2);
    }
}

// ---------------------------------------------------------------------------
extern "C" void kernel_launch(void* const* d_in, const int* in_sizes, int n_in,
                              void* d_out, int out_size, void* d_ws, size_t ws_size,
                              hipStream_t stream)
{
    const float* hid  = (const float*)d_in[0];
    const float* am   = (const float*)d_in[1];
    const float* Wq   = (const float*)d_in[2];
    const float* bq   = (const float*)d_in[3];
    const float* Wk   = (const float*)d_in[4];
    const float* bk   = (const float*)d_in[5];
    const float* Wv   = (const float*)d_in[6];
    const float* bv   = (const float*)d_in[7];
    const float* Wo   = (const float*)d_in[8];
    const float* bo   = (const float*)d_in[9];
    const float* ln1g = (const float*)d_in[10];
    const float* ln1b = (const float*)d_in[11];
    const float* Wi   = (const float*)d_in[12];
    const float* bi   = (const float*)d_in[13];
    const float* Wo2  = (const float*)d_in[14];
    const float* bo2  = (const float*)d_in[15];
    const float* ln2g = (const float*)d_in[16];
    const float* ln2b = (const float*)d_in[17];

    const long M  = (long)B_SZ * S_LEN;                 // 8192
    const long NQ = NQC;                                // 6291456

    unsigned short* W16 = (unsigned short*)d_ws;
    unsigned short* qb   = W16;
    unsigned short* kb   = W16 + NQ;
    unsigned short* vb   = W16 + 2 * NQ;
    unsigned short* vtb  = W16 + 3 * NQ;
    unsigned short* ctxb = W16 + 4 * NQ;
    unsigned short* hidb = W16 + 5 * NQ;
    unsigned short* wqt  = W16 + 6 * NQ;
    unsigned short* wkt  = wqt + 589824;
    unsigned short* wvt  = wkt + 589824;
    unsigned short* wot  = wvt + 589824;
    unsigned short* wit  = wot + 589824;
    unsigned short* wo2t = wit + 2359296;     // ends at u16 44826624
    float* tmp   = (float*)(W16 + 44826624);  // ends u16 57409536
    float* partB1 = (float*)(W16 + 57409536); // ends u16 69992448
    float* bcat  = (float*)(W16 + 69992448);
    float* partA0 = (float*)W16;
    float* partA1 = (float*)(W16 + 2 * NQ);
    unsigned short* interb = W16;
    unsigned short* attnb  = hidb;
    float* partB0 = (float*)(W16 + 4 * NQ);
    (void)ws_size; (void)in_sizes; (void)n_in; (void)out_size;

    transpose_k<<<dim3(24, 24), dim3(32, 8), 0, stream>>>(Wq, wqt, 768, 768);
    transpose_k<<<dim3(24, 24), dim3(32, 8), 0, stream>>>(Wk, wkt, 768, 768);
    transpose_k<<<dim3(24, 24), dim3(32, 8), 0, stream>>>(Wv, wvt, 768, 768);
    transpose_k<<<dim3(24, 24), dim3(32, 8), 0, stream>>>(Wo, wot, 768, 768);
    transpose_k<<<dim3(96, 24), dim3(32, 8), 0, stream>>>(Wi, wit, 768, 3072);
    transpose_k<<<dim3(24, 96), dim3(32, 8), 0, stream>>>(Wo2, wo2t, 3072, 768);
    conv_k<<<dim3((NQ / 4 + 255) / 256), dim3(256), 0, stream>>>(hid, hidb, NQ);
    bcat_k<<<dim3(9), dim3(256), 0, stream>>>(bq, bk, bv, bcat);

    dim3 blk(256);

    gemm_bf<2><<<dim3(1152), blk, 0, stream>>>(hidb, wqt, bcat, qb,
                                               M, 2304, 768, 18);

    vt_k<<<dim3(128, 24), blk, 0, stream>>>(vb, vtb);

    band_mfma_k<<<dim3(768), blk, 0, stream>>>(qb, kb, vtb, am, ctxb);
    glob_mfma_k<<<dim3(B_SZ * NHEAD), dim3(512), 0, stream>>>(qb, kb, vtb, am, ctxb);

    gemm_sp<<<dim3(768), blk, 0, stream>>>(ctxb, wot, partA0, partA1,
                                           M, 768, 384, 6, 384);
    ln2p_k<<<dim3(M), blk, 0, stream>>>(partA0, partA1, bo, hid,
                                        tmp, attnb, ln1g, ln1b);

    gemm_bf<1><<<dim3(1536), blk, 0, stream>>>(attnb, wit, bi, interb,
                                               M, 3072, 768, 24);

    gemm_sp<<<dim3(768), blk, 0, stream>>>(interb, wo2t, partB0, partB1,
                                           M, 768, 1536, 6, 384);
    ln2p_k<<<dim3(M), blk, 0, stream>>>(partB0, partB1, bo2, tmp,
                                        (float*)d_out, nullptr, ln2g, ln2b);
}

// Round 10
// 459.394 us; speedup vs baseline: 1.0275x; 1.0275x over previous
//
#include <hip/hip_runtime.h>
#include <math.h>

#define NHEAD 12
#define DH 64
#define S_LEN 4096
#define B_SZ 2
#define D_MODEL 768
#define FF_DIM 3072
#define WINSZ 128
#define NGLB 32
#define NEGV -1e9f
#define NQC 6291456L

typedef __attribute__((ext_vector_type(8))) short bf16x8;
typedef __attribute__((ext_vector_type(4))) float floatx4;

__device__ __forceinline__ unsigned short f2bf(float x) {
    union { float f; unsigned u; } v; v.f = x;
    unsigned r = v.u + 0x7fffu + ((v.u >> 16) & 1u);
    return (unsigned short)(r >> 16);
}
__device__ __forceinline__ float bf2f(unsigned short x) {
    union { unsigned u; float f; } v; v.u = ((unsigned)x) << 16;
    return v.f;
}

// fast GELU (tanh approx, |err| vs exact-erf gelu < ~3e-3), overflow-guarded
__device__ __forceinline__ float gelu_f(float x) {
    const float y = fminf(1.5957691216f * (x + 0.044715f * x * x * x), 80.f);
    const float t = __expf(y);
    return x * t * __builtin_amdgcn_rcpf(t + 1.f);
}

__device__ __forceinline__ void async_copy16(const unsigned short* g, unsigned short* l) {
    __builtin_amdgcn_global_load_lds(
        (const __attribute__((address_space(1))) void*)g,
        (__attribute__((address_space(3))) void*)l, 16, 0, 0);
}

// ---------------------------------------------------------------------------
// fp32 -> bf16 elementwise
// ---------------------------------------------------------------------------
__global__ __launch_bounds__(256) void conv_k(
    const float* __restrict__ x, unsigned short* __restrict__ y, long n)
{
    long i = ((long)blockIdx.x * 256 + threadIdx.x) * 4;
    if (i >= n) return;
    float4 v = *(const float4*)(x + i);
    ushort4 o;
    o.x = f2bf(v.x); o.y = f2bf(v.y); o.z = f2bf(v.z); o.w = f2bf(v.w);
    *(ushort4*)(y + i) = o;
}

// ---------------------------------------------------------------------------
// concat 3 x 768 biases -> 2304
// ---------------------------------------------------------------------------
__global__ __launch_bounds__(256) void bcat_k(
    const float* __restrict__ a, const float* __restrict__ b,
    const float* __restrict__ c, float* __restrict__ o)
{
    int i = blockIdx.x * 256 + threadIdx.x;
    if (i < 768) o[i] = a[i];
    else if (i < 1536) o[i] = b[i - 768];
    else if (i < 2304) o[i] = c[i - 1536];
}

// ---------------------------------------------------------------------------
// W (KxN fp32) -> WT (NxK bf16)
// ---------------------------------------------------------------------------
__global__ __launch_bounds__(256) void transpose_k(
    const float* __restrict__ W, unsigned short* __restrict__ WT, int K, int N)
{
    __shared__ float tile[32][33];
    const int tx = threadIdx.x, ty = threadIdx.y;
    const int n0 = blockIdx.x * 32, k0 = blockIdx.y * 32;
#pragma unroll
    for (int i = 0; i < 4; ++i)
        tile[ty + 8 * i][tx] = W[(long)(k0 + ty + 8 * i) * N + n0 + tx];
    __syncthreads();
#pragma unroll
    for (int i = 0; i < 4; ++i)
        WT[(long)(n0 + ty + 8 * i) * K + k0 + tx] = f2bf(tile[tx][ty + 8 * i]);
}

// ---------------------------------------------------------------------------
// V (B,NH,S,DH) bf16 -> Vt (B,NH,DH,S) bf16
// ---------------------------------------------------------------------------
__global__ __launch_bounds__(256) void vt_k(
    const unsigned short* __restrict__ v, unsigned short* __restrict__ vt)
{
    const int bh = blockIdx.y;
    const int s0 = blockIdx.x * 32;
    const int w = threadIdx.x >> 6, lane = threadIdx.x & 63;
    const unsigned short* src = v + ((long)bh * S_LEN + s0 + w * 8) * DH + lane;
    unsigned short r[8];
#pragma unroll
    for (int j = 0; j < 8; ++j) r[j] = src[j * DH];
    unsigned short* dst = vt + ((long)bh * DH + lane) * S_LEN + s0 + w * 8;
    ushort4 lo, hi;
    lo.x = r[0]; lo.y = r[1]; lo.z = r[2]; lo.w = r[3];
    hi.x = r[4]; hi.y = r[5]; hi.z = r[6]; hi.w = r[7];
    *(ushort4*)dst = lo;
    *(ushort4*)(dst + 4) = hi;
}

// ---------------------------------------------------------------------------
// bf16 MFMA GEMM, BK=64: half the barrier pairs of BK=32 (m97's ~20% barrier
// drain amortized). LDS 2x16KB. Staging: wave w covers rows [w*32,w*32+32)
// in 4 calls of 8 rows; lane's LDS slot = base + lane*16B (HW constraint),
// global chunk XOR-swizzled by row&7. Read: physical chunk = logical ^ row&7.
// EPI 1: fast gelu -> bf16
// EPI 2: fused QKV scatter (part uniform per block since 768 = 6*128) -> bf16
// ---------------------------------------------------------------------------
template <int EPI>
__global__ __launch_bounds__(256) void gemm_bf(
    const unsigned short* __restrict__ A, const unsigned short* __restrict__ BT,
    const float* __restrict__ bias, void* __restrict__ out,
    int M, int N, int K, int nx)
{
    __shared__ unsigned short As[128 * 64];
    __shared__ unsigned short Bs[128 * 64];
    const int tid = threadIdx.x;
    const int wave = tid >> 6, lane = tid & 63;
    const int t8 = (blockIdx.x & 7) * (gridDim.x >> 3) + (blockIdx.x >> 3);
    const int m0 = (t8 / nx) * 128, n0 = (t8 % nx) * 128;
    const int wr = (wave >> 1) * 64, wc = (wave & 1) * 64;

    floatx4 acc[4][4];
#pragma unroll
    for (int i = 0; i < 4; ++i)
#pragma unroll
        for (int j = 0; j < 4; ++j) acc[i][j] = (floatx4){0.f, 0.f, 0.f, 0.f};

    const int srow8 = lane >> 3;                 // row within 8-row group
    const int gchk = ((lane & 7) ^ srow8) * 8;   // swizzled global chunk (u16)
    const int ln15 = lane & 15, ln4 = lane >> 4, ln7 = lane & 7;

    for (int k0 = 0; k0 < K; k0 += 64) {
#pragma unroll
        for (int c = 0; c < 4; ++c) {
            const int rbase = wave * 32 + c * 8;
            async_copy16(A + (long)(m0 + rbase + srow8) * K + k0 + gchk, &As[rbase * 64]);
            async_copy16(BT + (long)(n0 + rbase + srow8) * K + k0 + gchk, &Bs[rbase * 64]);
        }
        __syncthreads();
#pragma unroll
        for (int ks = 0; ks < 2; ++ks) {
            const int p8 = ((ks * 4 + ln4) ^ ln7) * 8;
            bf16x8 af[4], bfr[4];
#pragma unroll
            for (int i = 0; i < 4; ++i) {
                af[i]  = *(const bf16x8*)&As[(wr + i * 16 + ln15) * 64 + p8];
                bfr[i] = *(const bf16x8*)&Bs[(wc + i * 16 + ln15) * 64 + p8];
            }
#pragma unroll
            for (int i = 0; i < 4; ++i)
#pragma unroll
                for (int j = 0; j < 4; ++j)
                    acc[i][j] = __builtin_amdgcn_mfma_f32_16x16x32_bf16(
                        af[i], bfr[j], acc[i][j], 0, 0, 0);
        }
        __syncthreads();
    }

    const int col_l = lane & 15, row_l = (lane >> 4) * 4;

    if (EPI == 1) {
#pragma unroll
        for (int i = 0; i < 4; ++i) {
            const int mb = m0 + wr + i * 16 + row_l;
#pragma unroll
            for (int rg = 0; rg < 4; ++rg) {
                unsigned short* orow = (unsigned short*)out + (long)(mb + rg) * N;
#pragma unroll
                for (int j = 0; j < 4; ++j) {
                    const int n = n0 + wc + j * 16 + col_l;
                    orow[n] = f2bf(gelu_f(acc[i][j][rg] + bias[n]));
                }
            }
        }
    } else {
        const int part = (n0 >= 1536) ? 2 : (n0 >= 768 ? 1 : 0);
        const float sc = (part == 0) ? 0.125f : 1.f;
        unsigned short* qkv = (unsigned short*)out + (long)part * NQC;
        long coloff[4];
        float bv[4];
#pragma unroll
        for (int j = 0; j < 4; ++j) {
            const int n = n0 + wc + j * 16 + col_l;
            const int nn = n - part * 768;
            coloff[j] = (long)(nn >> 6) * (S_LEN * DH) + (nn & 63);
            bv[j] = bias[n];
        }
#pragma unroll
        for (int i = 0; i < 4; ++i) {
            const int mb = m0 + wr + i * 16 + row_l;
#pragma unroll
            for (int rg = 0; rg < 4; ++rg) {
                const int m = mb + rg;
                const long rowoff = (long)(m >> 12) * (NHEAD * S_LEN * DH)
                                  + (long)(m & 4095) * DH;
#pragma unroll
                for (int j = 0; j < 4; ++j)
                    qkv[rowoff + coloff[j]] = f2bf((acc[i][j][rg] + bv[j]) * sc);
            }
        }
    }
}

// ---------------------------------------------------------------------------
// Split-K (x2) bf16 MFMA GEMM, BK=64: raw fp32 partials, no epilogue.
// ---------------------------------------------------------------------------
__global__ __launch_bounds__(256) void gemm_sp(
    const unsigned short* __restrict__ A, const unsigned short* __restrict__ BT,
    float* __restrict__ p0, float* __restrict__ p1,
    int M, int N, int K2, int nx, int ntile)
{
    __shared__ unsigned short As[128 * 64];
    __shared__ unsigned short Bs[128 * 64];
    const int tid = threadIdx.x;
    const int wave = tid >> 6, lane = tid & 63;
    const int t8 = (blockIdx.x & 7) * (gridDim.x >> 3) + (blockIdx.x >> 3);
    const int slice = t8 >= ntile;
    const int tile = t8 - slice * ntile;
    const int m0 = (tile / nx) * 128, n0 = (tile % nx) * 128;
    const int kbeg = slice * K2, kend = kbeg + K2;
    float* P = slice ? p1 : p0;
    const int wr = (wave >> 1) * 64, wc = (wave & 1) * 64;

    floatx4 acc[4][4];
#pragma unroll
    for (int i = 0; i < 4; ++i)
#pragma unroll
        for (int j = 0; j < 4; ++j) acc[i][j] = (floatx4){0.f, 0.f, 0.f, 0.f};

    const int srow8 = lane >> 3;
    const int gchk = ((lane & 7) ^ srow8) * 8;
    const int ln15 = lane & 15, ln4 = lane >> 4, ln7 = lane & 7;
    const long Kl = (long)K2 * 2;

    for (int k0 = kbeg; k0 < kend; k0 += 64) {
#pragma unroll
        for (int c = 0; c < 4; ++c) {
            const int rbase = wave * 32 + c * 8;
            async_copy16(A + (long)(m0 + rbase + srow8) * Kl + k0 + gchk, &As[rbase * 64]);
            async_copy16(BT + (long)(n0 + rbase + srow8) * Kl + k0 + gchk, &Bs[rbase * 64]);
        }
        __syncthreads();
#pragma unroll
        for (int ks = 0; ks < 2; ++ks) {
            const int p8 = ((ks * 4 + ln4) ^ ln7) * 8;
            bf16x8 af[4], bfr[4];
#pragma unroll
            for (int i = 0; i < 4; ++i) {
                af[i]  = *(const bf16x8*)&As[(wr + i * 16 + ln15) * 64 + p8];
                bfr[i] = *(const bf16x8*)&Bs[(wc + i * 16 + ln15) * 64 + p8];
            }
#pragma unroll
            for (int i = 0; i < 4; ++i)
#pragma unroll
                for (int j = 0; j < 4; ++j)
                    acc[i][j] = __builtin_amdgcn_mfma_f32_16x16x32_bf16(
                        af[i], bfr[j], acc[i][j], 0, 0, 0);
        }
        __syncthreads();
    }

    const int col_l = lane & 15, row_l = (lane >> 4) * 4;
#pragma unroll
    for (int i = 0; i < 4; ++i)
#pragma unroll
        for (int j = 0; j < 4; ++j) {
            const int n = n0 + wc + j * 16 + col_l;
#pragma unroll
            for (int rg = 0; rg < 4; ++rg) {
                const int m = m0 + wr + i * 16 + row_l + rg;
                P[(long)m * N + n] = acc[i][j][rg];
            }
        }
}

// ---------------------------------------------------------------------------
// MFMA band attention. One block per (b,h,chunk); 4 waves x 32 queries.
// ---------------------------------------------------------------------------
__global__ __launch_bounds__(256) void band_mfma_k(
    const unsigned short* __restrict__ q, const unsigned short* __restrict__ k,
    const unsigned short* __restrict__ vt, const float* __restrict__ am,
    unsigned short* __restrict__ ctx)
{
    __shared__ unsigned short Ks[32 * 72];
    __shared__ unsigned short Vs[64 * 40];
    __shared__ unsigned short Ps[4][32 * 40];

    const int blk = blockIdx.x;
    const int c = blk & 31;
    const int h = (blk >> 5) % NHEAD;
    const int b = blk / (32 * NHEAD);
    const int tid = threadIdx.x;
    const int wave = tid >> 6, lane = tid & 63;
    const long bh = (long)b * NHEAD + h;

    const unsigned short* kh  = k + bh * S_LEN * DH;
    const unsigned short* vth = vt + bh * (long)DH * S_LEN;
    const float* amb = am + (long)b * S_LEN;

    const int q0 = c * WINSZ + wave * 32;
    const int ln15 = lane & 15, ln4 = lane >> 4;

    bf16x8 qf[2][2];
#pragma unroll
    for (int nt = 0; nt < 2; ++nt)
#pragma unroll
        for (int ks = 0; ks < 2; ++ks)
            qf[nt][ks] = *(const bf16x8*)(q + (bh * S_LEN + q0 + nt * 16 + ln15) * DH
                                          + ks * 32 + ln4 * 8);

    floatx4 o[4][2];
#pragma unroll
    for (int mt = 0; mt < 4; ++mt)
#pragma unroll
        for (int nt = 0; nt < 2; ++nt) o[mt][nt] = (floatx4){0.f, 0.f, 0.f, 0.f};
    float m_r[2] = {-1e30f, -1e30f}, l_r[2] = {0.f, 0.f};

    const int sk_key = tid >> 3, sk_ch = tid & 7;
    const int sv_dim = tid & 63, sv_ch = tid >> 6;
    const bf16x8 zero8 = {0, 0, 0, 0, 0, 0, 0, 0};

    for (int tile = 0; tile < 13; ++tile) {
        const bool glob = (tile == 12);
        const int kbase = glob ? 0 : (c * WINSZ - WINSZ + tile * 32);

        __syncthreads();
        {
            int kpos = kbase + sk_key;
            bf16x8 val = zero8;
            if ((unsigned)kpos < (unsigned)S_LEN)
                val = *(const bf16x8*)(kh + (long)kpos * DH + sk_ch * 8);
            *(bf16x8*)(&Ks[sk_key * 72 + sk_ch * 8]) = val;
        }
        {
            int kc = kbase + sv_ch * 8;
            bf16x8 val = zero8;
            if (kc >= 0 && kc + 8 <= S_LEN)
                val = *(const bf16x8*)(vth + (long)sv_dim * S_LEN + kc);
            *(bf16x8*)(&Vs[sv_dim * 40 + sv_ch * 8]) = val;
        }
        __syncthreads();

        bf16x8 ak[2][2];
#pragma unroll
        for (int mt = 0; mt < 2; ++mt)
#pragma unroll
            for (int ks = 0; ks < 2; ++ks)
                ak[mt][ks] = *(const bf16x8*)(&Ks[(mt * 16 + ln15) * 72 + ks * 32 + ln4 * 8]);

        floatx4 s[2][2];
#pragma unroll
        for (int mt = 0; mt < 2; ++mt)
#pragma unroll
            for (int nt = 0; nt < 2; ++nt) {
                floatx4 acc = (floatx4){0.f, 0.f, 0.f, 0.f};
                acc = __builtin_amdgcn_mfma_f32_16x16x32_bf16(ak[mt][0], qf[nt][0], acc, 0, 0, 0);
                acc = __builtin_amdgcn_mfma_f32_16x16x32_bf16(ak[mt][1], qf[nt][1], acc, 0, 0, 0);
                s[mt][nt] = acc;
            }

#pragma unroll
        for (int mt = 0; mt < 2; ++mt) {
            const int kp0 = kbase + mt * 16 + ln4 * 4;
#pragma unroll
            for (int rg = 0; rg < 4; ++rg) {
                const int kpos = kp0 + rg;
                const bool kin = (unsigned)kpos < (unsigned)S_LEN;
                const float amv = kin ? amb[kpos] : 0.f;
#pragma unroll
                for (int nt = 0; nt < 2; ++nt) {
                    const int qpos = q0 + nt * 16 + ln15;
                    const int dlt = kpos > qpos ? kpos - qpos : qpos - kpos;
                    const bool valid = glob || (kpos >= NGLB && kin && dlt <= WINSZ);
                    s[mt][nt][rg] = valid ? s[mt][nt][rg] + amv : NEGV;
                }
            }
        }

        float alpha[2];
#pragma unroll
        for (int nt = 0; nt < 2; ++nt) {
            float mx = s[0][nt][0];
#pragma unroll
            for (int rg = 1; rg < 4; ++rg) mx = fmaxf(mx, s[0][nt][rg]);
#pragma unroll
            for (int rg = 0; rg < 4; ++rg) mx = fmaxf(mx, s[1][nt][rg]);
            mx = fmaxf(mx, __shfl_xor(mx, 16));
            mx = fmaxf(mx, __shfl_xor(mx, 32));
            const float mn = fmaxf(m_r[nt], mx);
            alpha[nt] = __expf(m_r[nt] - mn);
            m_r[nt] = mn;
        }

#pragma unroll
        for (int nt = 0; nt < 2; ++nt) {
            float sum = 0.f;
#pragma unroll
            for (int mt = 0; mt < 2; ++mt) {
                ushort4 pk;
#pragma unroll
                for (int rg = 0; rg < 4; ++rg) {
                    const float p = __expf(s[mt][nt][rg] - m_r[nt]);
                    sum += p;
                    ((unsigned short*)&pk)[rg] = f2bf(p);
                }
                *(ushort4*)(&Ps[wave][(nt * 16 + ln15) * 40 + mt * 16 + ln4 * 4]) = pk;
            }
            sum += __shfl_xor(sum, 16);
            sum += __shfl_xor(sum, 32);
            l_r[nt] = l_r[nt] * alpha[nt] + sum;
        }

#pragma unroll
        for (int mt = 0; mt < 4; ++mt)
#pragma unroll
            for (int nt = 0; nt < 2; ++nt)
#pragma unroll
                for (int rg = 0; rg < 4; ++rg) o[mt][nt][rg] *= alpha[nt];

        bf16x8 av[4], bp[2];
#pragma unroll
        for (int mt = 0; mt < 4; ++mt)
            av[mt] = *(const bf16x8*)(&Vs[(mt * 16 + ln15) * 40 + ln4 * 8]);
#pragma unroll
        for (int nt = 0; nt < 2; ++nt)
            bp[nt] = *(const bf16x8*)(&Ps[wave][(nt * 16 + ln15) * 40 + ln4 * 8]);
#pragma unroll
        for (int mt = 0; mt < 4; ++mt)
#pragma unroll
            for (int nt = 0; nt < 2; ++nt)
                o[mt][nt] = __builtin_amdgcn_mfma_f32_16x16x32_bf16(
                    av[mt], bp[nt], o[mt][nt], 0, 0, 0);
    }

    const float inv0 = 1.f / l_r[0], inv1 = 1.f / l_r[1];
#pragma unroll
    for (int nt = 0; nt < 2; ++nt) {
        const float inv = nt ? inv1 : inv0;
        const long row = (long)b * S_LEN + q0 + nt * 16 + ln15;
#pragma unroll
        for (int mt = 0; mt < 4; ++mt) {
            ushort4 ov;
#pragma unroll
            for (int rg = 0; rg < 4; ++rg)
                ((unsigned short*)&ov)[rg] = f2bf(o[mt][nt][rg] * inv);
            *(ushort4*)(ctx + row * D_MODEL + h * DH + mt * 16 + ln4 * 4) = ov;
        }
    }
}

// ---------------------------------------------------------------------------
// MFMA global-query attention. One block per (b,h); 8 waves x 512 keys/iter.
// ---------------------------------------------------------------------------
__global__ __launch_bounds__(512) void glob_mfma_k(
    const unsigned short* __restrict__ q, const unsigned short* __restrict__ k,
    const unsigned short* __restrict__ vt, const float* __restrict__ am,
    unsigned short* __restrict__ ctx)
{
    __shared__ unsigned short Ps[8][32 * 72];
    __shared__ float Om[64 * 36];
    __shared__ float mW[8][32], lW[8][32], lTot[32];

    const int bh = blockIdx.x;
    const int b = bh / NHEAD, h = bh % NHEAD;
    const int tid = threadIdx.x;
    const int wave = tid >> 6, lane = tid & 63;
    const int ln15 = lane & 15, ln4 = lane >> 4;

    const unsigned short* kh  = k + (long)bh * S_LEN * DH;
    const unsigned short* vth = vt + (long)bh * DH * S_LEN;
    const float* amb = am + (long)b * S_LEN;

    bf16x8 qf[2][2];
#pragma unroll
    for (int nt = 0; nt < 2; ++nt)
#pragma unroll
        for (int ks = 0; ks < 2; ++ks)
            qf[nt][ks] = *(const bf16x8*)(q + ((long)bh * S_LEN + nt * 16 + ln15) * DH
                                          + ks * 32 + ln4 * 8);

    floatx4 o[4][2];
#pragma unroll
    for (int mt = 0; mt < 4; ++mt)
#pragma unroll
        for (int nt = 0; nt < 2; ++nt) o[mt][nt] = (floatx4){0.f, 0.f, 0.f, 0.f};
    float m_r[2] = {-1e30f, -1e30f}, l_r[2] = {0.f, 0.f};

    for (int it = 0; it < 8; ++it) {
        const int kbase = it * 512 + wave * 64;

        bf16x8 ak[4][2];
#pragma unroll
        for (int mt = 0; mt < 4; ++mt)
#pragma unroll
            for (int ks = 0; ks < 2; ++ks)
                ak[mt][ks] = *(const bf16x8*)(kh + (long)(kbase + mt * 16 + ln15) * DH
                                              + ks * 32 + ln4 * 8);

        floatx4 s[4][2];
#pragma unroll
        for (int mt = 0; mt < 4; ++mt)
#pragma unroll
            for (int nt = 0; nt < 2; ++nt) {
                floatx4 acc = (floatx4){0.f, 0.f, 0.f, 0.f};
                acc = __builtin_amdgcn_mfma_f32_16x16x32_bf16(ak[mt][0], qf[nt][0], acc, 0, 0, 0);
                acc = __builtin_amdgcn_mfma_f32_16x16x32_bf16(ak[mt][1], qf[nt][1], acc, 0, 0, 0);
                s[mt][nt] = acc;
            }

#pragma unroll
        for (int mt = 0; mt < 4; ++mt) {
            const int kp0 = kbase + mt * 16 + ln4 * 4;
#pragma unroll
            for (int rg = 0; rg < 4; ++rg) {
                const float amv = amb[kp0 + rg];
#pragma unroll
                for (int nt = 0; nt < 2; ++nt) s[mt][nt][rg] += amv;
            }
        }

        float alpha[2];
#pragma unroll
        for (int nt = 0; nt < 2; ++nt) {
            float mx = s[0][nt][0];
#pragma unroll
            for (int mt = 0; mt < 4; ++mt)
#pragma unroll
                for (int rg = 0; rg < 4; ++rg) mx = fmaxf(mx, s[mt][nt][rg]);
            mx = fmaxf(mx, __shfl_xor(mx, 16));
            mx = fmaxf(mx, __shfl_xor(mx, 32));
            const float mn = fmaxf(m_r[nt], mx);
            alpha[nt] = __expf(m_r[nt] - mn);
            m_r[nt] = mn;
        }

#pragma unroll
        for (int nt = 0; nt < 2; ++nt) {
            float sum = 0.f;
#pragma unroll
            for (int mt = 0; mt < 4; ++mt) {
                ushort4 pk;
#pragma unroll
                for (int rg = 0; rg < 4; ++rg) {
                    const float p = __expf(s[mt][nt][rg] - m_r[nt]);
                    sum += p;
                    ((unsigned short*)&pk)[rg] = f2bf(p);
                }
                *(ushort4*)(&Ps[wave][(nt * 16 + ln15) * 72 + mt * 16 + ln4 * 4]) = pk;
            }
            sum += __shfl_xor(sum, 16);
            sum += __shfl_xor(sum, 32);
            l_r[nt] = l_r[nt] * alpha[nt] + sum;
        }

#pragma unroll
        for (int mt = 0; mt < 4; ++mt)
#pragma unroll
            for (int nt = 0; nt < 2; ++nt)
#pragma unroll
                for (int rg = 0; rg < 4; ++rg) o[mt][nt][rg] *= alpha[nt];

        bf16x8 av[4][2], bp[2][2];
#pragma unroll
        for (int mt = 0; mt < 4; ++mt)
#pragma unroll
            for (int ks = 0; ks < 2; ++ks)
                av[mt][ks] = *(const bf16x8*)(vth + (long)(mt * 16 + ln15) * S_LEN
                                              + kbase + ks * 32 + ln4 * 8);
#pragma unroll
        for (int nt = 0; nt < 2; ++nt)
#pragma unroll
            for (int ks = 0; ks < 2; ++ks)
                bp[nt][ks] = *(const bf16x8*)(&Ps[wave][(nt * 16 + ln15) * 72
                                              + ks * 32 + ln4 * 8]);
#pragma unroll
        for (int mt = 0; mt < 4; ++mt)
#pragma unroll
            for (int nt = 0; nt < 2; ++nt) {
                o[mt][nt] = __builtin_amdgcn_mfma_f32_16x16x32_bf16(
                    av[mt][0], bp[nt][0], o[mt][nt], 0, 0, 0);
                o[mt][nt] = __builtin_amdgcn_mfma_f32_16x16x32_bf16(
                    av[mt][1], bp[nt][1], o[mt][nt], 0, 0, 0);
            }
    }

    if (ln4 == 0) {
#pragma unroll
        for (int nt = 0; nt < 2; ++nt) {
            mW[wave][nt * 16 + ln15] = m_r[nt];
            lW[wave][nt * 16 + ln15] = l_r[nt];
        }
    }
    for (int i = tid; i < 64 * 36; i += 512) Om[i] = 0.f;
    __syncthreads();

    float f[2];
#pragma unroll
    for (int nt = 0; nt < 2; ++nt) {
        const int qq = nt * 16 + ln15;
        float mt_ = mW[0][qq];
#pragma unroll
        for (int w = 1; w < 8; ++w) mt_ = fmaxf(mt_, mW[w][qq]);
        float lt = 0.f;
#pragma unroll
        for (int w = 0; w < 8; ++w) lt += __expf(mW[w][qq] - mt_) * lW[w][qq];
        f[nt] = __expf(m_r[nt] - mt_);
        if (wave == 0 && ln4 == 0) lTot[qq] = lt;
    }
#pragma unroll
    for (int mt = 0; mt < 4; ++mt)
#pragma unroll
        for (int nt = 0; nt < 2; ++nt)
#pragma unroll
            for (int rg = 0; rg < 4; ++rg) o[mt][nt][rg] *= f[nt];

    for (int wv = 0; wv < 8; ++wv) {
        if (wave == wv) {
#pragma unroll
            for (int mt = 0; mt < 4; ++mt)
#pragma unroll
                for (int nt = 0; nt < 2; ++nt)
#pragma unroll
                    for (int rg = 0; rg < 4; ++rg)
                        Om[(mt * 16 + ln4 * 4 + rg) * 36 + nt * 16 + ln15] += o[mt][nt][rg];
        }
        __syncthreads();
    }

    const int qq = tid >> 4, d0 = (tid & 15) * 4;
    const float inv = 1.f / lTot[qq];
    ushort4 ov;
#pragma unroll
    for (int i = 0; i < 4; ++i)
        ((unsigned short*)&ov)[i] = f2bf(Om[(d0 + i) * 36 + qq] * inv);
    *(ushort4*)(ctx + ((long)b * S_LEN + qq) * D_MODEL + h * DH + d0) = ov;
}

// ---------------------------------------------------------------------------
// Fused split-K reduce + bias + residual + LayerNorm.
// ---------------------------------------------------------------------------
__global__ __launch_bounds__(256) void ln2p_k(
    const float* __restrict__ p0, const float* __restrict__ p1,
    const float* __restrict__ bias, const float* __restrict__ resid,
    float* __restrict__ out, unsigned short* __restrict__ out_bf,
    const float* __restrict__ gw, const float* __restrict__ bw)
{
    __shared__ float red[256];
    const long row = blockIdx.x;
    const long base = row * D_MODEL;
    const int t = threadIdx.x;
    float v0 = p0[base + t]       + p1[base + t]       + bias[t]       + resid[base + t];
    float v1 = p0[base + t + 256] + p1[base + t + 256] + bias[t + 256] + resid[base + t + 256];
    float v2 = p0[base + t + 512] + p1[base + t + 512] + bias[t + 512] + resid[base + t + 512];

    red[t] = v0 + v1 + v2;
    __syncthreads();
    for (int off = 128; off; off >>= 1) {
        if (t < off) red[t] += red[t + off];
        __syncthreads();
    }
    const float mu = red[0] * (1.f / 768.f);
    __syncthreads();

    float d0 = v0 - mu, d1 = v1 - mu, d2 = v2 - mu;
    red[t] = d0 * d0 + d1 * d1 + d2 * d2;
    __syncthreads();
    for (int off = 128; off; off >>= 1) {
        if (t < off) red[t] += red[t + off];
        __syncthreads();
    }
    const float var = red[0] * (1.f / 768.f);
    const float rs = rsqrtf(var + 1e-12f);

    const float y0 = d0 * rs * gw[t] + bw[t];
    const float y1 = d1 * rs * gw[t + 256] + bw[t + 256];
    const float y2 = d2 * rs * gw[t + 512] + bw[t + 512];
    if (out) {
        float* y = out + base;
        y[t] = y0; y[t + 256] = y1; y[t + 512] = y2;
    }
    if (out_bf) {
        unsigned short* yb = out_bf + base;
        yb[t] = f2bf(y0); yb[t + 256] = f2bf(y1); yb[t + 512] = f2bf(y2);
    }
}

// ---------------------------------------------------------------------------
extern "C" void kernel_launch(void* const* d_in, const int* in_sizes, int n_in,
                              void* d_out, int out_size, void* d_ws, size_t ws_size,
                              hipStream_t stream)
{
    const float* hid  = (const float*)d_in[0];
    const float* am   = (const float*)d_in[1];
    const float* Wq   = (const float*)d_in[2];
    const float* bq   = (const float*)d_in[3];
    const float* Wk   = (const float*)d_in[4];
    const float* bk   = (const float*)d_in[5];
    const float* Wv   = (const float*)d_in[6];
    const float* bv   = (const float*)d_in[7];
    const float* Wo   = (const float*)d_in[8];
    const float* bo   = (const float*)d_in[9];
    const float* ln1g = (const float*)d_in[10];
    const float* ln1b = (const float*)d_in[11];
    const float* Wi   = (const float*)d_in[12];
    const float* bi   = (const float*)d_in[13];
    const float* Wo2  = (const float*)d_in[14];
    const float* bo2  = (const float*)d_in[15];
    const float* ln2g = (const float*)d_in[16];
    const float* ln2b = (const float*)d_in[17];

    const long M  = (long)B_SZ * S_LEN;                 // 8192
    const long NQ = NQC;                                // 6291456

    unsigned short* W16 = (unsigned short*)d_ws;
    unsigned short* qb   = W16;
    unsigned short* kb   = W16 + NQ;
    unsigned short* vb   = W16 + 2 * NQ;
    unsigned short* vtb  = W16 + 3 * NQ;
    unsigned short* ctxb = W16 + 4 * NQ;
    unsigned short* hidb = W16 + 5 * NQ;
    unsigned short* wqt  = W16 + 6 * NQ;
    unsigned short* wkt  = wqt + 589824;
    unsigned short* wvt  = wkt + 589824;
    unsigned short* wot  = wvt + 589824;
    unsigned short* wit  = wot + 589824;
    unsigned short* wo2t = wit + 2359296;     // ends at u16 44826624
    float* tmp   = (float*)(W16 + 44826624);  // ends u16 57409536
    float* partB1 = (float*)(W16 + 57409536); // ends u16 69992448
    float* bcat  = (float*)(W16 + 69992448);
    float* partA0 = (float*)W16;
    float* partA1 = (float*)(W16 + 2 * NQ);
    unsigned short* interb = W16;
    unsigned short* attnb  = hidb;
    float* partB0 = (float*)(W16 + 4 * NQ);
    (void)ws_size; (void)in_sizes; (void)n_in; (void)out_size;

    transpose_k<<<dim3(24, 24), dim3(32, 8), 0, stream>>>(Wq, wqt, 768, 768);
    transpose_k<<<dim3(24, 24), dim3(32, 8), 0, stream>>>(Wk, wkt, 768, 768);
    transpose_k<<<dim3(24, 24), dim3(32, 8), 0, stream>>>(Wv, wvt, 768, 768);
    transpose_k<<<dim3(24, 24), dim3(32, 8), 0, stream>>>(Wo, wot, 768, 768);
    transpose_k<<<dim3(96, 24), dim3(32, 8), 0, stream>>>(Wi, wit, 768, 3072);
    transpose_k<<<dim3(24, 96), dim3(32, 8), 0, stream>>>(Wo2, wo2t, 3072, 768);
    conv_k<<<dim3((NQ / 4 + 255) / 256), dim3(256), 0, stream>>>(hid, hidb, NQ);
    bcat_k<<<dim3(9), dim3(256), 0, stream>>>(bq, bk, bv, bcat);

    dim3 blk(256);

    gemm_bf<2><<<dim3(1152), blk, 0, stream>>>(hidb, wqt, bcat, qb,
                                               M, 2304, 768, 18);

    vt_k<<<dim3(128, 24), blk, 0, stream>>>(vb, vtb);

    band_mfma_k<<<dim3(768), blk, 0, stream>>>(qb, kb, vtb, am, ctxb);
    glob_mfma_k<<<dim3(B_SZ * NHEAD), dim3(512), 0, stream>>>(qb, kb, vtb, am, ctxb);

    gemm_sp<<<dim3(768), blk, 0, stream>>>(ctxb, wot, partA0, partA1,
                                           M, 768, 384, 6, 384);
    ln2p_k<<<dim3(M), blk, 0, stream>>>(partA0, partA1, bo, hid,
                                        tmp, attnb, ln1g, ln1b);

    gemm_bf<1><<<dim3(1536), blk, 0, stream>>>(attnb, wit, bi, interb,
                                               M, 3072, 768, 24);

    gemm_sp<<<dim3(768), blk, 0, stream>>>(interb, wo2t, partB0, partB1,
                                           M, 768, 1536, 6, 384);
    ln2p_k<<<dim3(M), blk, 0, stream>>>(partB0, partB1, bo2, tmp,
                                        (float*)d_out, nullptr, ln2g, ln2b);
}